// Round 2
// baseline (414.645 us; speedup 1.0000x reference)
//
#include <hip/hip_runtime.h>
#include <hip/hip_cooperative_groups.h>
#include <hip/hip_bf16.h>
#include <stdint.h>

namespace cg = cooperative_groups;

#define Bn 8
#define Sn 4096
#define Hn 768
#define Dn 1024
#define Wn 2048

typedef __attribute__((ext_vector_type(8))) short short8;
typedef __attribute__((ext_vector_type(4))) short short4v;
typedef __attribute__((ext_vector_type(4))) float floatx4;

constexpr int GK = Hn;                 // 768
constexpr int LDS_A = 256 * 64;        // shorts per A tile buffer
constexpr int LDS_B = 128 * 64;        // shorts per B tile buffer
constexpr int LDS_T = LDS_A + LDS_B;   // 24576 shorts = 48 KiB per ring slot
constexpr int kLdsBytes = 3 * LDS_T * (int)sizeof(short);  // 147456
static_assert(kLdsBytes == 147456, "LDS budget");

__device__ __forceinline__ void load_lds16(const void* g, void* l) {
  __builtin_amdgcn_global_load_lds(
      (const __attribute__((address_space(1))) void*)g,
      (__attribute__((address_space(3))) void*)l, 16, 0, 0);
}

// ONE cooperative kernel: 256 blocks x 512 threads, 1 block/CU (144 KiB LDS),
// grid-wide barriers between phases. Eliminates 2 kernel-boundary drains and
// makes the whole op a single dispatch (visible in rocprof top-5 if >60us).
//
// phase 0: blocks [0,192): transpose proj_w (HxD fp32) -> B^T (DxH bf16),
//          4x (32x32) tiles per block. blocks [192,256): boundary table
//          starts[b][w] from sorted word_ids (32768 threads exactly).
// phase 1: segment mean + validity. 2048 waves x 8 words each; the 9 segment
//          boundaries per wave are prefetched with ONE global load + __shfl
//          broadcast so per-word work has no dependent-load chain on starts.
// phase 2: bf16 MFMA GEMM C = A@B^T + bias. 256x128 tile, BK=64, 8 waves,
//          3-slot LDS ring, counted vmcnt(6) (T2+T3+T4+T5 template from R1).
//          2 n-tiles per block sharing one m-strip (A panel L2-hot on 2nd).
__global__ __launch_bounds__(512, 2) void k_fused(
    const float* __restrict__ emb, const float* __restrict__ pw,
    const float* __restrict__ bias, const int* __restrict__ masks,
    const int* __restrict__ wid, short* wb, short* wa, int* starts,
    float* __restrict__ out, float* __restrict__ out_masks) {
  extern __shared__ __align__(16) short ls[];
  const int t = threadIdx.x;
  const int bid = blockIdx.x;
  cg::grid_group grid = cg::this_grid();

  // ---------------- phase 0: transpose ∥ boundary table ----------------
  if (bid < 192) {
    float* tile = (float*)ls;  // [32][33] fp32 = 4224 B of the dynamic LDS
    const int tx = t & 31, ty = t >> 5;  // 32 x 16
#pragma unroll 1
    for (int i = 0; i < 4; ++i) {
      const int bt = bid * 4 + i;  // 1024/32=32 d-tiles fastest, 24 h-tiles
      const int d0 = (bt & 31) * 32, h0 = (bt >> 5) * 32;
      tile[ty * 33 + tx] = pw[(size_t)(h0 + ty) * Dn + d0 + tx];
      tile[(ty + 16) * 33 + tx] = pw[(size_t)(h0 + ty + 16) * Dn + d0 + tx];
      __syncthreads();
      __hip_bfloat16 v0 = (__hip_bfloat16)tile[tx * 33 + ty];
      __hip_bfloat16 v1 = (__hip_bfloat16)tile[tx * 33 + ty + 16];
      wb[(size_t)(d0 + ty) * Hn + h0 + tx] = *(short*)&v0;
      wb[(size_t)(d0 + ty + 16) * Hn + h0 + tx] = *(short*)&v1;
      __syncthreads();
    }
  } else {
    const int g = (bid - 192) * 512 + t;  // 0 .. 32767 == Bn*Sn
    const int b = g >> 12, s = g & (Sn - 1);
    const int* wbi = wid + (size_t)b * Sn;
    int* sb = starts + b * (Wn + 1);
    const int cur = wbi[s];
    const int prev = (s == 0) ? -1 : wbi[s - 1];
    for (int ww = prev + 1; ww <= cur; ++ww) sb[ww] = s;
    if (s == Sn - 1)
      for (int ww = cur + 1; ww <= Wn; ++ww) sb[ww] = Sn;
  }
  __threadfence();
  grid.sync();

  // ---------------- phase 1: segment means + masks ----------------
  {
    const int wave = t >> 6, lane = t & 63;
    const int gw0 = (bid * 8 + wave) * 8;  // first of 8 consecutive words
    const int b = gw0 >> 11;               // 2048 words per batch
    const int w0 = gw0 & (Wn - 1);
    const int* sb = starts + b * (Wn + 1);
    // prefetch the 9 boundaries for this wave's 8 words (one load + shfl)
    const int pre = (lane < 9) ? sb[w0 + lane] : 0;
    const int* mb = masks + (size_t)b * Sn;
    const float* eb = emb + (size_t)b * Sn * Hn;

    for (int wi = 0; wi < 8; ++wi) {
      const int start = __shfl(pre, wi);
      const int end = __shfl(pre, wi + 1);
      const int count = end - start;

      bool allone = true;
      for (int s0 = start; s0 < end; s0 += 64) {
        const int idx = s0 + lane;
        allone = allone && ((idx < end) ? (mb[idx] == 1) : true);
      }
      const bool valid = (count > 0) && __all(allone);
      const float inv = valid ? 1.0f / (float)count : 0.0f;

      floatx4 sum[3] = {{0.f, 0.f, 0.f, 0.f}, {0.f, 0.f, 0.f, 0.f},
                        {0.f, 0.f, 0.f, 0.f}};
      int s = start;
      for (; s + 1 < end; s += 2) {
        const floatx4* r0 = (const floatx4*)(eb + (size_t)s * Hn);
        const floatx4* r1 = (const floatx4*)(eb + (size_t)(s + 1) * Hn);
#pragma unroll
        for (int j = 0; j < 3; ++j) sum[j] += r0[j * 64 + lane];
#pragma unroll
        for (int j = 0; j < 3; ++j) sum[j] += r1[j * 64 + lane];
      }
      if (s < end) {
        const floatx4* r0 = (const floatx4*)(eb + (size_t)s * Hn);
#pragma unroll
        for (int j = 0; j < 3; ++j) sum[j] += r0[j * 64 + lane];
      }

      const int w = w0 + wi;
      const size_t rowbase = ((size_t)b * Wn + w) * Hn;
#pragma unroll
      for (int j = 0; j < 3; ++j) {
        short4v o;
#pragma unroll
        for (int c = 0; c < 4; ++c) {
          __hip_bfloat16 h = (__hip_bfloat16)(sum[j][c] * inv);
          o[c] = *reinterpret_cast<short*>(&h);
        }
        *(short4v*)&wa[rowbase + (size_t)(j * 64 + lane) * 4] = o;
      }
      if (lane == 0) out_masks[(size_t)b * Wn + w] = valid ? 1.0f : 0.0f;
    }
  }
  __threadfence();
  grid.sync();

  // ---------------- phase 2: GEMM ----------------
  {
    const int lane = t & 63, wave = t >> 6;
    const int wm = wave >> 1, wn = wave & 1;  // 4 x 2 wave grid
    const int lane16 = lane & 15, quad = lane >> 4;
    const int swz = lane16 & 7;

    // 256 blocks: xcd = bid&7, each XCD owns 8 m-tiles x full N.
    const int xcd = bid & 7, o = bid >> 3;  // o in [0,32)
    const int m0 = (xcd * 8 + (o >> 2)) * 256;
    const int n0b = (o & 3) * 256;  // this block's two n-tiles: n0b, n0b+128

    const int rA = t >> 3;
    const int ssw = ((t & 7) ^ (rA & 7)) * 8;  // pre-swizzled source (T2)
    const short* gAs = (const short*)wa + (size_t)(m0 + rA) * GK + ssw;

#pragma unroll 1
    for (int nt = 0; nt < 2; ++nt) {
      const int n0 = n0b + nt * 128;
      const short* gBs = (const short*)wb + (size_t)(n0 + rA) * GK + ssw;

      auto stage_a3 = [&](int slot, int tt) {  // A chunks j=0,1,2
        short* d = ls + slot * LDS_T + t * 8;
        const short* g = gAs + tt * 64;
        load_lds16(g, d);
        load_lds16(g + (size_t)64 * GK, d + 4096);
        load_lds16(g + (size_t)128 * GK, d + 8192);
      };
      auto stage_b3 = [&](int slot, int tt) {  // A chunk j=3, B chunks j=0,1
        short* d = ls + slot * LDS_T + t * 8;
        load_lds16(gAs + tt * 64 + (size_t)192 * GK, d + 12288);
        load_lds16(gBs + tt * 64, d + 16384);
        load_lds16(gBs + tt * 64 + (size_t)64 * GK, d + 20480);
      };
      auto ld_af = [&](short8(&af)[2][2], int mib, const short* bufA) {
#pragma unroll
        for (int m2 = 0; m2 < 2; ++m2)
#pragma unroll
          for (int ks = 0; ks < 2; ++ks)
            af[m2][ks] = *(const short8*)&bufA[(wm * 64 + (mib + m2) * 16 + lane16) * 64 +
                                               ((((ks << 2) | quad) ^ swz) << 3)];
      };
      auto ld_bf = [&](short8(&bf)[4][2], const short* bufB) {
#pragma unroll
        for (int ni = 0; ni < 4; ++ni)
#pragma unroll
          for (int ks = 0; ks < 2; ++ks)
            bf[ni][ks] = *(const short8*)&bufB[(wn * 64 + ni * 16 + lane16) * 64 +
                                               ((((ks << 2) | quad) ^ swz) << 3)];
      };

      floatx4 acc[4][4];
#pragma unroll
      for (int i = 0; i < 4; ++i)
#pragma unroll
        for (int j = 0; j < 4; ++j) acc[i][j] = (floatx4){0.f, 0.f, 0.f, 0.f};

      auto mmac2 = [&](short8(&af)[2][2], short8(&bf)[4][2], int mib) {
        __builtin_amdgcn_s_setprio(1);
#pragma unroll
        for (int m2 = 0; m2 < 2; ++m2)
#pragma unroll
          for (int ni = 0; ni < 4; ++ni)
#pragma unroll
            for (int ks = 0; ks < 2; ++ks)
              acc[mib + m2][ni] = __builtin_amdgcn_mfma_f32_16x16x32_bf16(
                  af[m2][ks], bf[ni][ks], acc[mib + m2][ni], 0, 0, 0);
        __builtin_amdgcn_s_setprio(0);
      };

      // drain: epilogue stores / bias loads of the previous tile (or phase-1
      // stores) must not pollute the counted vmcnt bookkeeping below.
      asm volatile("s_waitcnt vmcnt(0)" ::: "memory");
      __builtin_amdgcn_sched_barrier(0);

      // prologue: stage tiles 0 and 1 (12 loads); vmcnt(6) -> tile 0 landed.
      stage_a3(0, 0);
      stage_b3(0, 0);
      stage_a3(1, 1);
      stage_b3(1, 1);
      asm volatile("s_waitcnt vmcnt(6)" ::: "memory");
      __builtin_amdgcn_sched_barrier(0);
      __builtin_amdgcn_s_barrier();

      int cur = 0;
#pragma unroll 1
      for (int tt = 0; tt < 12; ++tt) {  // 12 K-tiles of 64
        const short* bufA = ls + cur * LDS_T;
        const short* bufB = bufA + LDS_A;
        const int nx2 = (cur + 2 >= 3) ? cur - 1 : cur + 2;  // (tt+2)%3
        const bool st = tt < 10;
        short8 af[2][2], bf[4][2];

        // ---- phase A: mi 0,1 ----
        ld_af(af, 0, bufA);
        ld_bf(bf, bufB);
        if (st) stage_a3(nx2, tt + 2);
        __builtin_amdgcn_s_barrier();
        asm volatile("s_waitcnt lgkmcnt(0)" ::: "memory");
        __builtin_amdgcn_sched_barrier(0);
        mmac2(af, bf, 0);
        __builtin_amdgcn_s_barrier();

        // ---- phase B: mi 2,3 (bf reused in registers) ----
        ld_af(af, 2, bufA);
        if (st) stage_b3(nx2, tt + 2);
        if (tt < 10) {
          asm volatile("s_waitcnt vmcnt(6)" ::: "memory");  // counted (T4)
        } else if (tt == 10) {
          asm volatile("s_waitcnt vmcnt(0)" ::: "memory");  // tail drain
        }
        __builtin_amdgcn_sched_barrier(0);
        __builtin_amdgcn_s_barrier();
        asm volatile("s_waitcnt lgkmcnt(0)" ::: "memory");
        __builtin_amdgcn_sched_barrier(0);
        mmac2(af, bf, 2);
        __builtin_amdgcn_s_barrier();

        cur = (cur + 1 == 3) ? 0 : cur + 1;
      }

      // epilogue: bias here keeps the loop's vmcnt counting exact.
      float bv[4];
#pragma unroll
      for (int ni = 0; ni < 4; ++ni)
        bv[ni] = bias[n0 + wn * 64 + ni * 16 + lane16];

      // C/D layout: col = lane&15, row = quad*4 + r (m89/m91-verified)
#pragma unroll
      for (int mi = 0; mi < 4; ++mi) {
#pragma unroll
        for (int ni = 0; ni < 4; ++ni) {
          const int n = n0 + wn * 64 + ni * 16 + lane16;
#pragma unroll
          for (int r = 0; r < 4; ++r) {
            const int m = m0 + wm * 64 + mi * 16 + quad * 4 + r;
            out[(size_t)m * Dn + n] = acc[mi][ni][r] + bv[ni];
          }
        }
      }
    }
  }
}

extern "C" void kernel_launch(void* const* d_in, const int* in_sizes, int n_in,
                              void* d_out, int out_size, void* d_ws, size_t ws_size,
                              hipStream_t stream) {
  const float* emb    = (const float*)d_in[0];  // (8, 4096, 768)
  const float* proj_w = (const float*)d_in[1];  // (768, 1024)
  const float* proj_b = (const float*)d_in[2];  // (1024,)
  const int*   masks  = (const int*)d_in[3];    // (8, 4096)
  const int*   wid    = (const int*)d_in[4];    // (8, 4096)

  float* out = (float*)d_out;                       // (8, 2048, 1024) fp32
  float* out_masks = out + (size_t)Bn * Wn * Dn;    // (8, 2048) as 0.0/1.0

  short* wb = (short*)d_ws;                          // B^T: (1024, 768) bf16
  short* wa = wb + (size_t)Dn * Hn;                  // A:   (16384, 768) bf16
  int* starts = (int*)(wa + (size_t)Bn * Wn * Hn);   // (8, 2049) boundaries

  (void)hipFuncSetAttribute((const void*)k_fused,
                            hipFuncAttributeMaxDynamicSharedMemorySize, kLdsBytes);

  void* args[] = {(void*)&emb, (void*)&proj_w, (void*)&proj_b, (void*)&masks,
                  (void*)&wid, (void*)&wb,     (void*)&wa,     (void*)&starts,
                  (void*)&out, (void*)&out_masks};
  (void)hipLaunchCooperativeKernel((const void*)k_fused, dim3(256), dim3(512),
                                   args, kLdsBytes, stream);
}

// Round 3
// 211.724 us; speedup vs baseline: 1.9584x; 1.9584x over previous
//
#include <hip/hip_runtime.h>
#include <hip/hip_bf16.h>
#include <stdint.h>

#define Bn 8
#define Sn 4096
#define Hn 768
#define Dn 1024
#define Wn 2048

typedef __attribute__((ext_vector_type(8))) short short8;
typedef __attribute__((ext_vector_type(4))) short short4v;
typedef __attribute__((ext_vector_type(4))) float floatx4;

__device__ __forceinline__ void load_lds16(const void* g, void* l) {
  __builtin_amdgcn_global_load_lds(
      (const __attribute__((address_space(1))) void*)g,
      (__attribute__((address_space(3))) void*)l, 16, 0, 0);
}

// lane-parallel lower_bound over a sorted 4096-int array (wave-uniform result).
// Round 1: 64 coarse probes at stride 64; round 2: 64 fine probes in the
// 64-wide candidate window. 2 loads + 2 ballots; wid[b] is 16 KB -> L1-hot.
__device__ __forceinline__ int lb4096(const int* __restrict__ a, int x, int lane) {
  const int p = a[lane << 6];
  const unsigned long long m1 = __ballot(p < x);
  const int n1 = __popcll(m1);
  const int base = (n1 > 0 ? n1 - 1 : 0) << 6;
  const int q = a[base + lane];
  const unsigned long long m2 = __ballot(q < x);
  return base + __popcll(m2);
}

// -------- kernel 1: segment means + masks  ∥  proj_w transpose ------------------
// blocks [0, 4096): one wave per word (4 words/block). 4096 blocks -> 8 blocks/CU,
//   32 waves/CU: this grid size IS the latency hiding (do not shrink).
//   Word boundaries come from an in-wave binary search over sorted word_ids
//   (replaces the separate boundary-table kernel -> one fewer dispatch).
// blocks [4096, 4864): transpose proj_w (H x D fp32) -> B^T (D x H bf16).
__global__ __launch_bounds__(256) void k_front(const float* __restrict__ emb,
                                               const float* __restrict__ pw,
                                               const int* __restrict__ masks,
                                               const int* __restrict__ wid,
                                               __hip_bfloat16* __restrict__ wb,
                                               __hip_bfloat16* __restrict__ wa,
                                               float* __restrict__ out_masks) {
  const int bid = blockIdx.x;
  if (bid >= 4096) {
    // ---- transpose path (768 blocks, 32x32 tiles) ----
    __shared__ float tile[32][33];
    const int bt = bid - 4096;            // 32 x 24 tile grid
    const int d0 = (bt % 32) * 32, h0 = (bt / 32) * 32;
    const int tx = threadIdx.x & 31, ty = threadIdx.x >> 5;  // 32 x 8
#pragma unroll
    for (int i = 0; i < 32; i += 8)
      tile[ty + i][tx] = pw[(size_t)(h0 + ty + i) * Dn + d0 + tx];
    __syncthreads();
#pragma unroll
    for (int i = 0; i < 32; i += 8)
      wb[(size_t)(d0 + ty + i) * Hn + h0 + tx] = (__hip_bfloat16)tile[tx][ty + i];
    return;
  }

  // ---- word path ----
  const int b = bid >> 9;                    // 512 blocks per batch
  const int wave = threadIdx.x >> 6, lane = threadIdx.x & 63;
  const int w = (bid & 511) * 4 + wave;

  const int* wbi = wid + (size_t)b * Sn;
  const int start = lb4096(wbi, w, lane);
  const int end = lb4096(wbi, w + 1, lane);
  const int count = end - start;

  // parallel all-ones mask check (one 64-lane load per 64 subwords)
  const int* mb = masks + (size_t)b * Sn;
  bool allone = true;
  for (int s0 = start; s0 < end; s0 += 64) {
    const int idx = s0 + lane;
    allone = allone && ((idx < end) ? (mb[idx] == 1) : true);
  }
  const bool valid = (count > 0) && __all(allone);
  const float inv = valid ? 1.0f / (float)count : 0.0f;

  floatx4 sum[3] = {{0.f, 0.f, 0.f, 0.f}, {0.f, 0.f, 0.f, 0.f}, {0.f, 0.f, 0.f, 0.f}};
  const float* eb = emb + (size_t)b * Sn * Hn;
  int s = start;
  for (; s + 1 < end; s += 2) {
    const floatx4* r0 = (const floatx4*)(eb + (size_t)s * Hn);
    const floatx4* r1 = (const floatx4*)(eb + (size_t)(s + 1) * Hn);
#pragma unroll
    for (int j = 0; j < 3; ++j) sum[j] += r0[j * 64 + lane];
#pragma unroll
    for (int j = 0; j < 3; ++j) sum[j] += r1[j * 64 + lane];
  }
  if (s < end) {
    const floatx4* r0 = (const floatx4*)(eb + (size_t)s * Hn);
#pragma unroll
    for (int j = 0; j < 3; ++j) sum[j] += r0[j * 64 + lane];
  }

  const size_t rowbase = ((size_t)b * Wn + w) * Hn;
#pragma unroll
  for (int j = 0; j < 3; ++j) {
    short4v o;
#pragma unroll
    for (int c = 0; c < 4; ++c) {
      __hip_bfloat16 h = (__hip_bfloat16)(sum[j][c] * inv);
      o[c] = *reinterpret_cast<short*>(&h);
    }
    *(short4v*)&wa[rowbase + (size_t)(j * 64 + lane) * 4] = o;
  }
  if (lane == 0) out_masks[(size_t)b * Wn + w] = valid ? 1.0f : 0.0f;
}

// ------------- kernel 2: bf16 MFMA GEMM  C = A @ B + bias -----------------------
// A: (M=16384, K=768) bf16, Bt: (N=1024, K=768) bf16, C: fp32.
// 128x128 block tile, BK=64 as TWO concatenated BK=32 panels (identical
// per-panel layout to the validated m97 structure -> keeps global_load_lds
// lane-contiguity and fragment-read pattern), 32 MFMA per barrier interval,
// 12 barriers instead of 24. XCD-aware swizzle: each XCD owns a strip of
// 16 m-tiles x all 8 n-tiles (n fastest) so A-tiles stay L2-resident per XCD.
// Epilogue stores are NON-TEMPORAL: out (64 MB) is never re-read; keeping it
// out of L2 preserves A/B panel residency for the K-loop.
__global__ __launch_bounds__(256) void k_gemm(const short* __restrict__ A,
                                              const short* __restrict__ Bt,
                                              const float* __restrict__ bias,
                                              float* __restrict__ out) {
  constexpr int K = Hn;   // 768
  constexpr int N = Dn;   // 1024
  __shared__ __align__(16) short lsA[2][128 * 32];
  __shared__ __align__(16) short lsB[2][128 * 32];

  const int t = threadIdx.x;
  const int lane = t & 63, wave = t >> 6;
  const int wm = wave >> 1, wn = wave & 1;
  const int lane16 = lane & 15, quad = lane >> 4;

  const int linear = blockIdx.x;          // 1024 blocks
  const int xcd = linear & 7;
  const int o = linear >> 3;              // per-XCD ordinal, 0..127
  const int m0 = (xcd * 16 + (o >> 3)) * 128;
  const int n0 = (o & 7) * 128;

  const int lrow = t >> 2;
  const int lcol = (t & 3) * 8;
  const short* gA0 = A + (size_t)(m0 + lrow) * K + lcol;
  const short* gB0 = Bt + (size_t)(n0 + lrow) * K + lcol;
  const int loff = lrow * 32 + lcol;

  // bias hoisted out of the K-loop
  float bv[4];
#pragma unroll
  for (int ni = 0; ni < 4; ++ni)
    bv[ni] = bias[n0 + wn * 64 + ni * 16 + lane16];

  floatx4 acc[4][4];
#pragma unroll
  for (int i = 0; i < 4; ++i)
#pragma unroll
    for (int j = 0; j < 4; ++j) acc[i][j] = (floatx4){0.f, 0.f, 0.f, 0.f};

  for (int k0 = 0; k0 < K; k0 += 64) {
    // panel 0: k0..k0+31, panel 1: k0+32..k0+63
    load_lds16(gA0 + k0,                    &lsA[0][loff]);
    load_lds16(gA0 + (size_t)64 * K + k0,   &lsA[0][loff + 64 * 32]);
    load_lds16(gA0 + k0 + 32,               &lsA[1][loff]);
    load_lds16(gA0 + (size_t)64 * K + k0 + 32, &lsA[1][loff + 64 * 32]);
    load_lds16(gB0 + k0,                    &lsB[0][loff]);
    load_lds16(gB0 + (size_t)64 * K + k0,   &lsB[0][loff + 64 * 32]);
    load_lds16(gB0 + k0 + 32,               &lsB[1][loff]);
    load_lds16(gB0 + (size_t)64 * K + k0 + 32, &lsB[1][loff + 64 * 32]);
    __syncthreads();

#pragma unroll
    for (int sp = 0; sp < 2; ++sp) {
      short8 af[4], bf[4];
#pragma unroll
      for (int mi = 0; mi < 4; ++mi)
        af[mi] = *(const short8*)&lsA[sp][(wm * 64 + mi * 16 + lane16) * 32 + quad * 8];
#pragma unroll
      for (int ni = 0; ni < 4; ++ni)
        bf[ni] = *(const short8*)&lsB[sp][(wn * 64 + ni * 16 + lane16) * 32 + quad * 8];

#pragma unroll
      for (int mi = 0; mi < 4; ++mi)
#pragma unroll
        for (int ni = 0; ni < 4; ++ni)
          acc[mi][ni] = __builtin_amdgcn_mfma_f32_16x16x32_bf16(af[mi], bf[ni], acc[mi][ni], 0, 0, 0);
    }
    __syncthreads();
  }

  // epilogue: C/D layout col = lane&15, row = quad*4 + r  (m89/m91-verified)
#pragma unroll
  for (int mi = 0; mi < 4; ++mi) {
#pragma unroll
    for (int ni = 0; ni < 4; ++ni) {
      const int n = n0 + wn * 64 + ni * 16 + lane16;
#pragma unroll
      for (int r = 0; r < 4; ++r) {
        const int m = m0 + wm * 64 + mi * 16 + quad * 4 + r;
        __builtin_nontemporal_store(acc[mi][ni][r] + bv[ni], &out[(size_t)m * N + n]);
      }
    }
  }
}

extern "C" void kernel_launch(void* const* d_in, const int* in_sizes, int n_in,
                              void* d_out, int out_size, void* d_ws, size_t ws_size,
                              hipStream_t stream) {
  const float* emb    = (const float*)d_in[0];  // (8, 4096, 768)
  const float* proj_w = (const float*)d_in[1];  // (768, 1024)
  const float* proj_b = (const float*)d_in[2];  // (1024,)
  const int*   masks  = (const int*)d_in[3];    // (8, 4096)
  const int*   wid    = (const int*)d_in[4];    // (8, 4096)

  float* out = (float*)d_out;                       // (8, 2048, 1024) fp32
  float* out_masks = out + (size_t)Bn * Wn * Dn;    // (8, 2048) as 0.0/1.0

  __hip_bfloat16* wb = (__hip_bfloat16*)d_ws;            // B^T: (1024, 768) bf16
  __hip_bfloat16* wa = wb + (size_t)Dn * Hn;             // A:   (16384, 768) bf16

  // 1. segment means + masks (one wave per word, boundaries via in-wave
  //    binary search) ∥ proj_w transpose (768 trailing blocks)
  k_front<<<dim3(4096 + 768), 256, 0, stream>>>(emb, proj_w, masks, wid, wb, wa,
                                                out_masks);

  // 2. projection GEMM + bias (XCD-swizzled 1-D grid, BK=64 two-panel,
  //    non-temporal C stores)
  k_gemm<<<dim3(1024), 256, 0, stream>>>((const short*)wa, (const short*)wb,
                                         proj_b, out);
}

// Round 4
// 204.963 us; speedup vs baseline: 2.0230x; 1.0330x over previous
//
#include <hip/hip_runtime.h>
#include <hip/hip_bf16.h>
#include <stdint.h>

#define Bn 8
#define Sn 4096
#define Hn 768
#define Dn 1024
#define Wn 2048

typedef __attribute__((ext_vector_type(8))) short short8;
typedef __attribute__((ext_vector_type(4))) short short4v;
typedef __attribute__((ext_vector_type(4))) float floatx4;

__device__ __forceinline__ void load_lds16(const void* g, void* l) {
  __builtin_amdgcn_global_load_lds(
      (const __attribute__((address_space(1))) void*)g,
      (__attribute__((address_space(3))) void*)l, 16, 0, 0);
}

// lane-parallel lower_bound over a sorted 4096-int array (wave-uniform result).
__device__ __forceinline__ int lb4096(const int* __restrict__ a, int x, int lane) {
  const int p = a[lane << 6];
  const unsigned long long m1 = __ballot(p < x);
  const int n1 = __popcll(m1);
  const int base = (n1 > 0 ? n1 - 1 : 0) << 6;
  const int q = a[base + lane];
  const unsigned long long m2 = __ballot(q < x);
  return base + __popcll(m2);
}

// -------- kernel 1: segment means + masks  ∥  proj_w transpose ------------------
// blocks [0, 4096): one wave per word; boundaries via in-wave binary search.
// blocks [4096, 4864): transpose proj_w (H x D fp32) -> B^T (D x H bf16).
__global__ __launch_bounds__(256) void k_front(const float* __restrict__ emb,
                                               const float* __restrict__ pw,
                                               const int* __restrict__ masks,
                                               const int* __restrict__ wid,
                                               __hip_bfloat16* __restrict__ wb,
                                               __hip_bfloat16* __restrict__ wa,
                                               float* __restrict__ out_masks) {
  const int bid = blockIdx.x;
  if (bid >= 4096) {
    __shared__ float tile[32][33];
    const int bt = bid - 4096;            // 32 x 24 tile grid
    const int d0 = (bt % 32) * 32, h0 = (bt / 32) * 32;
    const int tx = threadIdx.x & 31, ty = threadIdx.x >> 5;  // 32 x 8
#pragma unroll
    for (int i = 0; i < 32; i += 8)
      tile[ty + i][tx] = pw[(size_t)(h0 + ty + i) * Dn + d0 + tx];
    __syncthreads();
#pragma unroll
    for (int i = 0; i < 32; i += 8)
      wb[(size_t)(d0 + ty + i) * Hn + h0 + tx] = (__hip_bfloat16)tile[tx][ty + i];
    return;
  }

  const int b = bid >> 9;                    // 512 blocks per batch
  const int wave = threadIdx.x >> 6, lane = threadIdx.x & 63;
  const int w = (bid & 511) * 4 + wave;

  const int* wbi = wid + (size_t)b * Sn;
  const int start = lb4096(wbi, w, lane);
  const int end = lb4096(wbi, w + 1, lane);
  const int count = end - start;

  const int* mb = masks + (size_t)b * Sn;
  bool allone = true;
  for (int s0 = start; s0 < end; s0 += 64) {
    const int idx = s0 + lane;
    allone = allone && ((idx < end) ? (mb[idx] == 1) : true);
  }
  const bool valid = (count > 0) && __all(allone);
  const float inv = valid ? 1.0f / (float)count : 0.0f;

  floatx4 sum[3] = {{0.f, 0.f, 0.f, 0.f}, {0.f, 0.f, 0.f, 0.f}, {0.f, 0.f, 0.f, 0.f}};
  const float* eb = emb + (size_t)b * Sn * Hn;
  int s = start;
  for (; s + 1 < end; s += 2) {
    const floatx4* r0 = (const floatx4*)(eb + (size_t)s * Hn);
    const floatx4* r1 = (const floatx4*)(eb + (size_t)(s + 1) * Hn);
#pragma unroll
    for (int j = 0; j < 3; ++j) sum[j] += r0[j * 64 + lane];
#pragma unroll
    for (int j = 0; j < 3; ++j) sum[j] += r1[j * 64 + lane];
  }
  if (s < end) {
    const floatx4* r0 = (const floatx4*)(eb + (size_t)s * Hn);
#pragma unroll
    for (int j = 0; j < 3; ++j) sum[j] += r0[j * 64 + lane];
  }

  const size_t rowbase = ((size_t)b * Wn + w) * Hn;
#pragma unroll
  for (int j = 0; j < 3; ++j) {
    short4v o;
#pragma unroll
    for (int c = 0; c < 4; ++c) {
      __hip_bfloat16 h = (__hip_bfloat16)(sum[j][c] * inv);
      o[c] = *reinterpret_cast<short*>(&h);
    }
    *(short4v*)&wa[rowbase + (size_t)(j * 64 + lane) * 4] = o;
  }
  if (lane == 0) out_masks[(size_t)b * Wn + w] = valid ? 1.0f : 0.0f;
}

// ------------- kernel 2: bf16 MFMA GEMM  C = A @ B^T + bias ---------------------
// A: (M=16384, K=768) bf16, Bt: (N=1024, K=768) bf16, C fp32.
// 256x256 tile, BK=64, 512 thr = 8 waves (2M x 4N, 128x64 out/wave).
// 256 blocks = EXACTLY 1 per CU (no scheduling tail). Double-buffered 128 KiB
// dynamic LDS; tile t+1's 8 stage-loads issued in phases 0-1 of tile t, so the
// tile-boundary __syncthreads() (vmcnt(0) == "t+1 resident") is nearly free:
// per-tile compute ~2500 cy >> HBM latency. 512 block-MFMAs between drains
// (4x the m97 structure), 12 drains total. Swizzle/fragments identical to the
// round-1-verified code. Block map mt=bid&63, nt=bid>>6: the 4 blocks sharing
// an A panel land on the same XCD (64 % 8 == 0) -> A panel L2-resident.
constexpr int GK = Hn;            // 768
constexpr int TS = 256 * 64;      // shorts per A (or B) region = 32 KiB
constexpr int kGemmLds = 2 * 2 * TS * (int)sizeof(short);  // 131072 B
static_assert(kGemmLds == 131072, "LDS budget");

__global__ __launch_bounds__(512, 2) void k_gemm(const short* __restrict__ A,
                                                 const short* __restrict__ Bt,
                                                 const float* __restrict__ bias,
                                                 float* __restrict__ out) {
  extern __shared__ __align__(16) short ls[];  // [2][A 16384 | B 16384]

  const int t = threadIdx.x;  // 0..511
  const int lane = t & 63, wave = t >> 6;
  const int wm = wave >> 2, wn = wave & 3;        // 2 x 4 wave grid
  const int lane16 = lane & 15, quad = lane >> 4;
  const int swz = lane16 & 7;

  const int mt = blockIdx.x & 63, nt = blockIdx.x >> 6;
  const int m0 = mt * 256, n0 = nt * 256;

  // staging: thread t covers rows rS + j*64 (j=0..3), physical 16B slot t&7;
  // pre-swizzled source col slot = (t&7) ^ (rS&7)  ((j*64)&7==0 -> row&7==rS&7)
  const int rS = t >> 3;
  const int csw = ((t & 7) ^ (rS & 7)) * 8;  // shorts
  const short* gAs = A + (size_t)(m0 + rS) * GK + csw;
  const short* gBs = Bt + (size_t)(n0 + rS) * GK + csw;
  const int dst0 = t * 8;  // = rS*64 + (t&7)*8

  auto stage_a = [&](int buf, int kt) {  // 4 loads: A rows rS+{0,64,128,192}
    short* d = ls + buf * 2 * TS + dst0;
    const short* g = gAs + kt * 64;
#pragma unroll
    for (int j = 0; j < 4; ++j) load_lds16(g + (size_t)(j * 64) * GK, d + j * 4096);
  };
  auto stage_b = [&](int buf, int kt) {  // 4 loads: B rows rS+{0,64,128,192}
    short* d = ls + buf * 2 * TS + TS + dst0;
    const short* g = gBs + kt * 64;
#pragma unroll
    for (int j = 0; j < 4; ++j) load_lds16(g + (size_t)(j * 64) * GK, d + j * 4096);
  };

  auto ld_a = [&](short8(&af)[4][2], int qm, const short* bufA) {
#pragma unroll
    for (int mf = 0; mf < 4; ++mf)
#pragma unroll
      for (int ks = 0; ks < 2; ++ks)
        af[mf][ks] = *(const short8*)&bufA[(wm * 128 + qm * 64 + mf * 16 + lane16) * 64 +
                                           ((((ks << 2) | quad) ^ swz) << 3)];
  };
  auto ld_b = [&](short8(&bf)[2][2], int qn, const short* bufB) {
#pragma unroll
    for (int nf = 0; nf < 2; ++nf)
#pragma unroll
      for (int ks = 0; ks < 2; ++ks)
        bf[nf][ks] = *(const short8*)&bufB[(wn * 64 + qn * 32 + nf * 16 + lane16) * 64 +
                                           ((((ks << 2) | quad) ^ swz) << 3)];
  };

  floatx4 acc[8][4];
#pragma unroll
  for (int i = 0; i < 8; ++i)
#pragma unroll
    for (int j = 0; j < 4; ++j) acc[i][j] = (floatx4){0.f, 0.f, 0.f, 0.f};

  auto mm = [&](short8(&af)[4][2], short8(&bf)[2][2], int qm, int qn) {
    __builtin_amdgcn_s_setprio(1);
#pragma unroll
    for (int mf = 0; mf < 4; ++mf)
#pragma unroll
      for (int nf = 0; nf < 2; ++nf)
#pragma unroll
        for (int ks = 0; ks < 2; ++ks)
          acc[qm * 4 + mf][qn * 2 + nf] = __builtin_amdgcn_mfma_f32_16x16x32_bf16(
              af[mf][ks], bf[nf][ks], acc[qm * 4 + mf][qn * 2 + nf], 0, 0, 0);
    __builtin_amdgcn_s_setprio(0);
  };

  // prologue: tile 0 -> buf0
  stage_a(0, 0);
  stage_b(0, 0);
  __syncthreads();

#pragma unroll 1
  for (int kt = 0; kt < 12; ++kt) {  // 12 K-tiles of 64
    const short* bufA = ls + (kt & 1) * 2 * TS;
    const short* bufB = bufA + TS;
    const int nb = (kt + 1) & 1;
    short8 af[4][2], b0[2][2], b1[2][2];

    // phase 0: quadrant (qm0,qn0); issue next tile's A stages early
    ld_a(af, 0, bufA);
    ld_b(b0, 0, bufB);
    if (kt < 11) stage_a(nb, kt + 1);
    mm(af, b0, 0, 0);

    // phase 1: (qm0,qn1); issue next tile's B stages
    ld_b(b1, 1, bufB);
    if (kt < 11) stage_b(nb, kt + 1);
    mm(af, b1, 0, 1);

    // phase 2: (qm1,qn1)  (af overwritten after qm0 fully consumed)
    ld_a(af, 1, bufA);
    mm(af, b1, 1, 1);

    // phase 3: (qm1,qn0)  (b0 still live)
    mm(af, b0, 1, 0);

    // boundary: drains vmcnt (next tile resident -- its loads had >=2 phases
    // of lead) + lgkm, and fences; this is the only sync per K-tile.
    __syncthreads();
  }

  // epilogue
  float bv[4];
#pragma unroll
  for (int nf = 0; nf < 4; ++nf) bv[nf] = bias[n0 + wn * 64 + nf * 16 + lane16];

  // C/D layout: col = lane&15, row = quad*4 + r (m89/m91-verified)
#pragma unroll
  for (int mg = 0; mg < 8; ++mg) {
#pragma unroll
    for (int ng = 0; ng < 4; ++ng) {
      const int n = n0 + wn * 64 + ng * 16 + lane16;
#pragma unroll
      for (int r = 0; r < 4; ++r) {
        const int m = m0 + wm * 128 + mg * 16 + quad * 4 + r;
        __builtin_nontemporal_store(acc[mg][ng][r] + bv[ng], &out[(size_t)m * Dn + n]);
      }
    }
  }
}

extern "C" void kernel_launch(void* const* d_in, const int* in_sizes, int n_in,
                              void* d_out, int out_size, void* d_ws, size_t ws_size,
                              hipStream_t stream) {
  const float* emb    = (const float*)d_in[0];  // (8, 4096, 768)
  const float* proj_w = (const float*)d_in[1];  // (768, 1024)
  const float* proj_b = (const float*)d_in[2];  // (1024,)
  const int*   masks  = (const int*)d_in[3];    // (8, 4096)
  const int*   wid    = (const int*)d_in[4];    // (8, 4096)

  float* out = (float*)d_out;                       // (8, 2048, 1024) fp32
  float* out_masks = out + (size_t)Bn * Wn * Dn;    // (8, 2048) as 0.0/1.0

  __hip_bfloat16* wb = (__hip_bfloat16*)d_ws;            // B^T: (1024, 768) bf16
  __hip_bfloat16* wa = wb + (size_t)Dn * Hn;             // A:   (16384, 768) bf16

  // 1. segment means + masks (wave per word, in-wave binary search)
  //    ∥ proj_w transpose (768 trailing blocks)
  k_front<<<dim3(4096 + 768), 256, 0, stream>>>(emb, proj_w, masks, wid, wb, wa,
                                                out_masks);

  // 2. projection GEMM + bias: 256x256 tiles, 256 blocks (1/CU), dbuf LDS.
  (void)hipFuncSetAttribute((const void*)k_gemm,
                            hipFuncAttributeMaxDynamicSharedMemorySize, kGemmLds);
  k_gemm<<<dim3(256), 512, kGemmLds, stream>>>((const short*)wa, (const short*)wb,
                                               proj_b, out);
}

// Round 6
// 204.375 us; speedup vs baseline: 2.0288x; 1.0029x over previous
//
#include <hip/hip_runtime.h>
#include <hip/hip_bf16.h>
#include <stdint.h>

#define Bn 8
#define Sn 4096
#define Hn 768
#define Dn 1024
#define Wn 2048

typedef __attribute__((ext_vector_type(8))) short short8;
typedef __attribute__((ext_vector_type(4))) short short4v;
typedef __attribute__((ext_vector_type(4))) float floatx4;

__device__ __forceinline__ void load_lds16(const void* g, void* l) {
  __builtin_amdgcn_global_load_lds(
      (const __attribute__((address_space(1))) void*)g,
      (__attribute__((address_space(3))) void*)l, 16, 0, 0);
}

// lane-parallel lower_bound over a sorted 4096-int array (wave-uniform result).
__device__ __forceinline__ int lb4096(const int* __restrict__ a, int x, int lane) {
  const int p = a[lane << 6];
  const unsigned long long m1 = __ballot(p < x);
  const int n1 = __popcll(m1);
  const int base = (n1 > 0 ? n1 - 1 : 0) << 6;
  const int q = a[base + lane];
  const unsigned long long m2 = __ballot(q < x);
  return base + __popcll(m2);
}

// -------- kernel 1: proj_w transpose  ∥  segment means + masks ------------------
// blocks [0, 768): transpose proj_w (H x D fp32) -> B^T (D x H bf16). Placed
//   FIRST in the grid so it overlaps the word blocks' ramp instead of running
//   as a serial tail after them (round-4 had it last).
// blocks [768, 4864): one wave per word; boundaries via in-wave binary search.
//   4096 word-blocks -> 8 blocks/CU, 32 waves/CU: this grid size IS the
//   latency hiding (do not shrink).
__global__ __launch_bounds__(256) void k_front(const float* __restrict__ emb,
                                               const float* __restrict__ pw,
                                               const int* __restrict__ masks,
                                               const int* __restrict__ wid,
                                               __hip_bfloat16* __restrict__ wb,
                                               __hip_bfloat16* __restrict__ wa,
                                               float* __restrict__ out_masks) {
  const int bid = blockIdx.x;
  if (bid < 768) {
    __shared__ float tile[32][33];
    const int bt = bid;                   // 32 x 24 tile grid
    const int d0 = (bt % 32) * 32, h0 = (bt / 32) * 32;
    const int tx = threadIdx.x & 31, ty = threadIdx.x >> 5;  // 32 x 8
#pragma unroll
    for (int i = 0; i < 32; i += 8)
      tile[ty + i][tx] = pw[(size_t)(h0 + ty + i) * Dn + d0 + tx];
    __syncthreads();
#pragma unroll
    for (int i = 0; i < 32; i += 8)
      wb[(size_t)(d0 + ty + i) * Hn + h0 + tx] = (__hip_bfloat16)tile[tx][ty + i];
    return;
  }

  const int wbid = bid - 768;                // 0 .. 4095
  const int b = wbid >> 9;                   // 512 blocks per batch
  const int wave = threadIdx.x >> 6, lane = threadIdx.x & 63;
  const int w = (wbid & 511) * 4 + wave;

  const int* wbi = wid + (size_t)b * Sn;
  const int start = lb4096(wbi, w, lane);
  const int end = lb4096(wbi, w + 1, lane);
  const int count = end - start;

  const int* mb = masks + (size_t)b * Sn;
  bool allone = true;
  for (int s0 = start; s0 < end; s0 += 64) {
    const int idx = s0 + lane;
    allone = allone && ((idx < end) ? (mb[idx] == 1) : true);
  }
  const bool valid = (count > 0) && __all(allone);
  const float inv = valid ? 1.0f / (float)count : 0.0f;

  floatx4 sum[3] = {{0.f, 0.f, 0.f, 0.f}, {0.f, 0.f, 0.f, 0.f}, {0.f, 0.f, 0.f, 0.f}};
  const float* eb = emb + (size_t)b * Sn * Hn;
  int s = start;
  for (; s + 1 < end; s += 2) {
    const floatx4* r0 = (const floatx4*)(eb + (size_t)s * Hn);
    const floatx4* r1 = (const floatx4*)(eb + (size_t)(s + 1) * Hn);
#pragma unroll
    for (int j = 0; j < 3; ++j) sum[j] += r0[j * 64 + lane];
#pragma unroll
    for (int j = 0; j < 3; ++j) sum[j] += r1[j * 64 + lane];
  }
  if (s < end) {
    const floatx4* r0 = (const floatx4*)(eb + (size_t)s * Hn);
#pragma unroll
    for (int j = 0; j < 3; ++j) sum[j] += r0[j * 64 + lane];
  }

  const size_t rowbase = ((size_t)b * Wn + w) * Hn;
#pragma unroll
  for (int j = 0; j < 3; ++j) {
    short4v o;
#pragma unroll
    for (int c = 0; c < 4; ++c) {
      __hip_bfloat16 h = (__hip_bfloat16)(sum[j][c] * inv);
      o[c] = *reinterpret_cast<short*>(&h);
    }
    *(short4v*)&wa[rowbase + (size_t)(j * 64 + lane) * 4] = o;
  }
  if (lane == 0) out_masks[(size_t)b * Wn + w] = valid ? 1.0f : 0.0f;
}

// ------------- kernel 2: bf16 MFMA GEMM  C = A @ B^T + bias ---------------------
// A: (M=16384, K=768) bf16, Bt: (N=1024, K=768) bf16, C fp32.
// 256x256 tile, BK=64, 512 thr = 8 waves (2M x 4N, 128x64 out/wave).
// 256 blocks = EXACTLY 1 per CU. Double-buffered 128 KiB dynamic LDS; next
// tile's 8 stage-loads issued in phases 0-1 of the current tile, so the
// boundary __syncthreads() drain is nearly free (loads get ~3 phases of lead).
// R5: last K-tile (kt=11) is PEELED with the epilogue fused in — each acc
// quadrant is stored (nontemporal) right after its final MFMA phase, so ~3/4
// of the 64 MB C-store traffic overlaps the last tile's ds_read+MFMA instead
// of running as a pure-BW serial tail. Bias hoisted pre-loop (every boundary
// sync drains vmcnt; no counted waits in this schedule to pollute).
constexpr int GK = Hn;            // 768
constexpr int TS = 256 * 64;      // shorts per A (or B) region = 32 KiB
constexpr int kGemmLds = 2 * 2 * TS * (int)sizeof(short);  // 131072 B
static_assert(kGemmLds == 131072, "LDS budget");

__global__ __launch_bounds__(512, 2) void k_gemm(const short* __restrict__ A,
                                                 const short* __restrict__ Bt,
                                                 const float* __restrict__ bias,
                                                 float* __restrict__ out) {
  extern __shared__ __align__(16) short ls[];  // [2][A 16384 | B 16384]

  const int t = threadIdx.x;  // 0..511
  const int lane = t & 63, wave = t >> 6;
  const int wm = wave >> 2, wn = wave & 3;        // 2 x 4 wave grid
  const int lane16 = lane & 15, quad = lane >> 4;
  const int swz = lane16 & 7;

  const int mt = blockIdx.x & 63, nt = blockIdx.x >> 6;
  const int m0 = mt * 256, n0 = nt * 256;

  // staging: thread t covers rows rS + j*64 (j=0..3), physical 16B slot t&7;
  // pre-swizzled source col slot = (t&7) ^ (rS&7)  ((j*64)&7==0 -> row&7==rS&7)
  const int rS = t >> 3;
  const int csw = ((t & 7) ^ (rS & 7)) * 8;  // shorts
  const short* gAs = A + (size_t)(m0 + rS) * GK + csw;
  const short* gBs = Bt + (size_t)(n0 + rS) * GK + csw;
  const int dst0 = t * 8;  // = rS*64 + (t&7)*8

  auto stage_a = [&](int buf, int kt) {  // 4 loads: A rows rS+{0,64,128,192}
    short* d = ls + buf * 2 * TS + dst0;
    const short* g = gAs + kt * 64;
#pragma unroll
    for (int j = 0; j < 4; ++j) load_lds16(g + (size_t)(j * 64) * GK, d + j * 4096);
  };
  auto stage_b = [&](int buf, int kt) {  // 4 loads: B rows rS+{0,64,128,192}
    short* d = ls + buf * 2 * TS + TS + dst0;
    const short* g = gBs + kt * 64;
#pragma unroll
    for (int j = 0; j < 4; ++j) load_lds16(g + (size_t)(j * 64) * GK, d + j * 4096);
  };

  auto ld_a = [&](short8(&af)[4][2], int qm, const short* bufA) {
#pragma unroll
    for (int mf = 0; mf < 4; ++mf)
#pragma unroll
      for (int ks = 0; ks < 2; ++ks)
        af[mf][ks] = *(const short8*)&bufA[(wm * 128 + qm * 64 + mf * 16 + lane16) * 64 +
                                           ((((ks << 2) | quad) ^ swz) << 3)];
  };
  auto ld_b = [&](short8(&bf)[2][2], int qn, const short* bufB) {
#pragma unroll
    for (int nf = 0; nf < 2; ++nf)
#pragma unroll
      for (int ks = 0; ks < 2; ++ks)
        bf[nf][ks] = *(const short8*)&bufB[(wn * 64 + qn * 32 + nf * 16 + lane16) * 64 +
                                           ((((ks << 2) | quad) ^ swz) << 3)];
  };

  floatx4 acc[8][4];
#pragma unroll
  for (int i = 0; i < 8; ++i)
#pragma unroll
    for (int j = 0; j < 4; ++j) acc[i][j] = (floatx4){0.f, 0.f, 0.f, 0.f};

  auto mm = [&](short8(&af)[4][2], short8(&bf)[2][2], int qm, int qn) {
    __builtin_amdgcn_s_setprio(1);
#pragma unroll
    for (int mf = 0; mf < 4; ++mf)
#pragma unroll
      for (int nf = 0; nf < 2; ++nf)
#pragma unroll
        for (int ks = 0; ks < 2; ++ks)
          acc[qm * 4 + mf][qn * 2 + nf] = __builtin_amdgcn_mfma_f32_16x16x32_bf16(
              af[mf][ks], bf[nf][ks], acc[qm * 4 + mf][qn * 2 + nf], 0, 0, 0);
    __builtin_amdgcn_s_setprio(0);
  };

  // bias hoisted (legal: every boundary __syncthreads drains vmcnt)
  float bv[4];
#pragma unroll
  for (int nf = 0; nf < 4; ++nf) bv[nf] = bias[n0 + wn * 64 + nf * 16 + lane16];

  // C/D layout: col = lane&15, row = quad*4 + r (m89/m91-verified)
  auto store_quad = [&](int qm, int qn) {
#pragma unroll
    for (int mf = 0; mf < 4; ++mf) {
#pragma unroll
      for (int nf = 0; nf < 2; ++nf) {
        const int n = n0 + wn * 64 + (qn * 2 + nf) * 16 + lane16;
#pragma unroll
        for (int r = 0; r < 4; ++r) {
          const int m = m0 + wm * 128 + (qm * 4 + mf) * 16 + quad * 4 + r;
          __builtin_nontemporal_store(acc[qm * 4 + mf][qn * 2 + nf][r] + bv[qn * 2 + nf],
                                      &out[(size_t)m * Dn + n]);
        }
      }
    }
  };

  // prologue: tile 0 -> buf0
  stage_a(0, 0);
  stage_b(0, 0);
  __syncthreads();

#pragma unroll 1
  for (int kt = 0; kt < 11; ++kt) {  // K-tiles 0..10 (kt=11 peeled below)
    const short* bufA = ls + (kt & 1) * 2 * TS;
    const short* bufB = bufA + TS;
    const int nb = (kt + 1) & 1;
    short8 af[4][2], b0[2][2], b1[2][2];

    // phase 0: quadrant (qm0,qn0); issue next tile's A stages early
    ld_a(af, 0, bufA);
    ld_b(b0, 0, bufB);
    stage_a(nb, kt + 1);
    mm(af, b0, 0, 0);

    // phase 1: (qm0,qn1); issue next tile's B stages
    ld_b(b1, 1, bufB);
    stage_b(nb, kt + 1);
    mm(af, b1, 0, 1);

    // phase 2: (qm1,qn1)
    ld_a(af, 1, bufA);
    mm(af, b1, 1, 1);

    // phase 3: (qm1,qn0)
    mm(af, b0, 1, 0);

    // boundary: drains vmcnt (next tile resident -- its loads had >=2 phases
    // of lead) + lgkm; the only sync per K-tile.
    __syncthreads();
  }

  // ---- peeled last K-tile (kt=11): epilogue fused into the phases ----
  {
    const short* bufA = ls + (11 & 1) * 2 * TS;
    const short* bufB = bufA + TS;
    short8 af[4][2], b0[2][2], b1[2][2];

    ld_a(af, 0, bufA);
    ld_b(b0, 0, bufB);
    mm(af, b0, 0, 0);
    store_quad(0, 0);          // overlaps with remaining ds_read+MFMA

    ld_b(b1, 1, bufB);
    mm(af, b1, 0, 1);
    store_quad(0, 1);

    ld_a(af, 1, bufA);
    mm(af, b1, 1, 1);
    store_quad(1, 1);

    mm(af, b0, 1, 0);
    store_quad(1, 0);
  }
}

extern "C" void kernel_launch(void* const* d_in, const int* in_sizes, int n_in,
                              void* d_out, int out_size, void* d_ws, size_t ws_size,
                              hipStream_t stream) {
  const float* emb    = (const float*)d_in[0];  // (8, 4096, 768)
  const float* proj_w = (const float*)d_in[1];  // (768, 1024)
  const float* proj_b = (const float*)d_in[2];  // (1024,)
  const int*   masks  = (const int*)d_in[3];    // (8, 4096)
  const int*   wid    = (const int*)d_in[4];    // (8, 4096)

  float* out = (float*)d_out;                       // (8, 2048, 1024) fp32
  float* out_masks = out + (size_t)Bn * Wn * Dn;    // (8, 2048) as 0.0/1.0

  __hip_bfloat16* wb = (__hip_bfloat16*)d_ws;            // B^T: (1024, 768) bf16
  __hip_bfloat16* wa = wb + (size_t)Dn * Hn;             // A:   (16384, 768) bf16

  // 1. transpose (first 768 blocks) ∥ segment means + masks (4096 blocks)
  k_front<<<dim3(768 + 4096), 256, 0, stream>>>(emb, proj_w, masks, wid, wb, wa,
                                                out_masks);

  // 2. projection GEMM + bias: 256x256 tiles, 256 blocks (1/CU), dbuf LDS,
  //    fused store-epilogue in peeled last K-tile.
  (void)hipFuncSetAttribute((const void*)k_gemm,
                            hipFuncAttributeMaxDynamicSharedMemorySize, kGemmLds);
  k_gemm<<<dim3(256), 512, kGemmLds, stream>>>((const short*)wa, (const short*)wb,
                                               proj_b, out);
}